// Round 13
// baseline (56.136 us; speedup 1.0000x reference)
//
#include <hip/hip_runtime.h>

// B=2, N=512, C_IN=16, C_OUT=16, HID=64
#define NQ   512
#define CI   16
#define CO   16
#define HIDN 64

typedef __attribute__((ext_vector_type(8))) short bf16x8;
typedef __attribute__((ext_vector_type(4))) float f32x4;
typedef __attribute__((ext_vector_type(4))) unsigned u32x4;
typedef __attribute__((ext_vector_type(2))) unsigned u32x2;

// packed bf16 convert: low16 = bf16(a), high16 = bf16(b)
__device__ __forceinline__ unsigned cvt_pk_bf16(float a, float b) {
    unsigned r;
    asm("v_cvt_pk_bf16_f32 %0, %1, %2" : "=v"(r) : "v"(a), "v"(b));
    return r;
}

// ---------------------------------------------------------------------------
// PROFILING ROUND: r10 kernel (best, 25.3us) with grid x3. Copies rep=1,2
// perform IDENTICAL work but write to disjoint d_ws regions -> one ~75us
// dispatch that finally outlasts the harness fillBuffer dispatches and
// surfaces real counters (VGPR, occupancy, VALUBusy, MfmaUtil, LDS conflicts,
// WRITE-derived store bandwidth). d_out result identical to r10.
// ---------------------------------------------------------------------------
__global__ __launch_bounds__(256, 4) void fused_mfma_kernel(
    const float* __restrict__ features,   // [1024,16]
    const float* __restrict__ geometry,   // [1024,3]
    const float* __restrict__ W1,         // [64,4]
    const float* __restrict__ b1,         // [64]
    const float* __restrict__ W2,         // [256,64]
    const float* __restrict__ b2,         // [256]
    float* __restrict__ out,              // [2,512,512,16]
    float* __restrict__ alt)              // d_ws scratch (2 output-sized slabs) or null
{
    __shared__ __attribute__((aligned(16))) unsigned short Mhi[CO * HIDN]; // swizzled [i][k]
    __shared__ __attribute__((aligned(16))) unsigned short Mlo[CO * HIDN];
    __shared__ __attribute__((aligned(16))) float W1_sm[HIDN * 4];
    __shared__ float b1_sm[HIDN];
    __shared__ float c_sm[CO];
    __shared__ float f_sm[CI];

    const int bid0 = blockIdx.x;
    const int rep  = bid0 >> 11;         // 0 = real output, 1/2 = ws copies
    const int bid  = bid0 & 2047;
    float* obase = out;
    if (rep == 1) obase = alt;
    else if (rep == 2) obase = alt + 8388608;   // 33.5 MB / 4

    const int zb  = bid >> 1;            // z*512 + b
    const int a0  = (bid & 1) << 8;
    const int z   = zb >> 9;
    const int b   = zb & 511;
    const int tid = threadIdx.x;

    // ---- coop param staging ----
    W1_sm[tid] = W1[tid];                // 256 floats
    if (tid < HIDN) b1_sm[tid] = b1[tid];
    if (tid < CI)   f_sm[tid]  = features[zb * CI + tid];
    __syncthreads();

    const int wv    = tid >> 6;
    const int lane  = tid & 63;
    const int col   = lane & 15;         // = i for A-frag, = a-offset for B-frag
    const int g     = lane >> 4;
    const int abase = a0 + wv * 64;

    // ---- geometry / rel ----
    const float gbx = geometry[(z * NQ + b) * 3 + 0];
    const float gby = geometry[(z * NQ + b) * 3 + 1];
    const float gbz = geometry[(z * NQ + b) * 3 + 2];
    float rel[4][4];
    #pragma unroll
    for (int t = 0; t < 4; ++t) {
        const float* ga = geometry + (size_t)(z * NQ + abase + t * 16 + col) * 3;
        float rx = gbx - ga[0], ry = gby - ga[1], rz = gbz - ga[2];
        rel[t][0] = rx; rel[t][1] = ry; rel[t][2] = rz;
        rel[t][3] = sqrtf(fmaf(rx, rx, fmaf(ry, ry, rz * rz)) + 1e-12f);
    }

    // ---- stage A: M (f32) -> bf16 hi/lo planes in LDS, swizzled ----
    {
        const int i  = tid >> 4;         // 0..15
        const int k4 = (tid & 15) << 2;  // 0,4,..,60
        f32x4 m = {0.f, 0.f, 0.f, 0.f};
        #pragma unroll
        for (int j = 0; j < CI; ++j) {
            const f32x4 w2 = *reinterpret_cast<const f32x4*>(&W2[(i * CI + j) * HIDN + k4]);
            const float fj = f_sm[j];
            #pragma unroll
            for (int p = 0; p < 4; ++p) m[p] = fmaf(fj, w2[p], m[p]);
        }
        const unsigned h0 = cvt_pk_bf16(m[0], m[1]);
        const unsigned h1 = cvt_pk_bf16(m[2], m[3]);
        const float f0 = __builtin_bit_cast(float, h0 << 16);
        const float f1 = __builtin_bit_cast(float, h0 & 0xffff0000u);
        const float f2 = __builtin_bit_cast(float, h1 << 16);
        const float f3 = __builtin_bit_cast(float, h1 & 0xffff0000u);
        const unsigned l0 = cvt_pk_bf16(m[0] - f0, m[1] - f1);
        const unsigned l1 = cvt_pk_bf16(m[2] - f2, m[3] - f3);
        const int bir = (k4 << 1) ^ ((i & 7) << 4);   // swizzled byte-in-row
        *reinterpret_cast<u32x2*>(reinterpret_cast<char*>(Mhi) + i * 128 + bir) = (u32x2){h0, h1};
        *reinterpret_cast<u32x2*>(reinterpret_cast<char*>(Mlo) + i * 128 + bir) = (u32x2){l0, l1};
    }
    if (tid < CO) {
        float acc = 0.f;
        #pragma unroll
        for (int j = 0; j < CI; ++j)
            acc = fmaf(f_sm[j], b2[tid * CI + j], acc);
        c_sm[tid] = acc;
    }
    __syncthreads();

    // ---- A fragments: one ds_read_b128 per (part,kc) ----
    bf16x8 Af[2][2];   // [part][kc]
    #pragma unroll
    for (int kc = 0; kc < 2; ++kc) {
        const int bir = (kc * 64 + g * 16) ^ ((col & 7) << 4);
        Af[0][kc] = *reinterpret_cast<const bf16x8*>(reinterpret_cast<const char*>(Mhi) + col * 128 + bir);
        Af[1][kc] = *reinterpret_cast<const bf16x8*>(reinterpret_cast<const char*>(Mlo) + col * 128 + bir);
    }

    // ---- accumulator init: lane (col,g) holds D^T rows i = g*4+r ----
    f32x4 cin;
    #pragma unroll
    for (int r = 0; r < 4; ++r) cin[r] = c_sm[g * 4 + r];
    f32x4 acc[4];
    #pragma unroll
    for (int t = 0; t < 4; ++t) acc[t] = cin;

    // ---- main: hv (B-frag: n=a=col, k=g*8+j), 2 MFMAs (hi+lo) per (t,kc) ----
    #pragma unroll
    for (int kc = 0; kc < 2; ++kc) {
        f32x4 w[8]; float bbias[8];
        #pragma unroll
        for (int j = 0; j < 8; ++j) {
            const int h = kc * 32 + g * 8 + j;
            w[j]     = *reinterpret_cast<const f32x4*>(&W1_sm[h * 4]);  // broadcast LDS
            bbias[j] = b1_sm[h];
        }
        #pragma unroll
        for (int t = 0; t < 4; ++t) {
            float hv[8];
            #pragma unroll
            for (int j = 0; j < 8; ++j) {
                float x = bbias[j];
                x = fmaf(rel[t][0], w[j][0], x);
                x = fmaf(rel[t][1], w[j][1], x);
                x = fmaf(rel[t][2], w[j][2], x);
                x = fmaf(rel[t][3], w[j][3], x);
                // gelu (tanh approx, sigmoid form)
                float q = fmaf(x * x, 0.044715f, 1.0f);
                float e = __builtin_amdgcn_exp2f((-2.3022082f * x) * q);
                hv[j]   = x * __builtin_amdgcn_rcpf(1.0f + e);
            }
            u32x4 up;
            #pragma unroll
            for (int p = 0; p < 4; ++p)
                up[p] = cvt_pk_bf16(hv[2 * p], hv[2 * p + 1]);
            const bf16x8 av = __builtin_bit_cast(bf16x8, up);
            acc[t] = __builtin_amdgcn_mfma_f32_16x16x32_bf16(Af[0][kc], av, acc[t], 0, 0, 0);
            acc[t] = __builtin_amdgcn_mfma_f32_16x16x32_bf16(Af[1][kc], av, acc[t], 0, 0, 0);
        }
    }

    // ---- epilogue: row a = abase+t*16+col, cols i = g*4..g*4+3 -> dwordx4 ----
    #pragma unroll
    for (int t = 0; t < 4; ++t) {
        float* op = obase + (((size_t)(z * NQ + abase + t * 16 + col)) * NQ + b) * CO + g * 4;
        *reinterpret_cast<f32x4*>(op) = acc[t];
    }
}

extern "C" void kernel_launch(void* const* d_in, const int* in_sizes, int n_in,
                              void* d_out, int out_size, void* d_ws, size_t ws_size,
                              hipStream_t stream) {
    const float* features = (const float*)d_in[0];
    const float* geometry = (const float*)d_in[1];
    const float* W1       = (const float*)d_in[2];
    const float* b1       = (const float*)d_in[3];
    const float* W2       = (const float*)d_in[4];
    const float* b2       = (const float*)d_in[5];
    float* out = (float*)d_out;

    const size_t slab = (size_t)2 * NQ * NQ * CO * sizeof(float);   // 33.5 MB
    if (ws_size >= 2 * slab) {
        // profiling: x3 grid, copies write to ws slabs -> one ~75us dispatch
        fused_mfma_kernel<<<6144, 256, 0, stream>>>(
            features, geometry, W1, b1, W2, b2, out, (float*)d_ws);
    } else {
        fused_mfma_kernel<<<2048, 256, 0, stream>>>(
            features, geometry, W1, b1, W2, b2, out, out /*unused: rep==0 only*/);
    }
}